// Round 5
// baseline (38339.847 us; speedup 1.0000x reference)
//
#include <hip/hip_runtime.h>
#include <math.h>

#define T_STEPS 2048
#define BATCH   64
#define IDIM    256
#define HDIM    512
#define K1      768
#define H3      1536
#define NGROUP  4
#define NSLICE  32
#define RPG     16
#define THREADS 512

// ---------------------------------------------------------------------------
// Round-5 = round-0 dataflow (4 syncs: a1, a2, p3, cb; proven 25.98 ms),
// restructured to cut stall:
//  * per-wave stamping: producing wave drains its OWN vmcnt(0), lane0 bumps
//    an LDS counter (ds_add_rtn, workgroup scope); finisher wave stores the
//    global stamp. Publish __syncthreads barriers (4/step) eliminated.
//  * x(t+1) written to zh in the B9->B10 window; GEMM1-x hoisted after the
//    p3 stamp (fills the p3 round-trip window; acc carried across loop).
//    Stage-1's x-write barrier eliminated. Barriers/step: 13 -> 8.
//  * HBM out[] stores issued AFTER the cb stamp (drain off critical path).
// Arithmetic identical to round-0 (same MFMA order, same reduces) -> same
// absmax.
// ---------------------------------------------------------------------------

// dword-unit workspace offsets
#define OFF_A1  0          // 64*512 f32
#define OFF_A2  32768      // 64*512 f32
#define OFF_CB  65536      // 64*512 bf16 (packed, stored as ushort)
#define OFF_P3  81920      // 64 rows * 32 slices * 2 f32
#define OFF_ST  86016      // stamps: 4 stages * 4 groups * 32 ints
#define N_ST    512

typedef __attribute__((ext_vector_type(8))) __bf16 bf16x8;
typedef __attribute__((ext_vector_type(4))) float f32x4;

__device__ __forceinline__ f32x4 MFMA(bf16x8 a, bf16x8 b, f32x4 c) {
    return __builtin_amdgcn_mfma_f32_16x16x32_bf16(a, b, c, 0, 0, 0);
}

__device__ __forceinline__ float2 gload2(const float* p) {
    unsigned long long v = __hip_atomic_load((const unsigned long long*)p,
                                             __ATOMIC_RELAXED, __HIP_MEMORY_SCOPE_AGENT);
    return __builtin_bit_cast(float2, v);
}
__device__ __forceinline__ void gstore2(float* p, float a, float b) {
    float2 v = {a, b};
    __hip_atomic_store((unsigned long long*)p, __builtin_bit_cast(unsigned long long, v),
                       __ATOMIC_RELAXED, __HIP_MEMORY_SCOPE_AGENT);
}
__device__ __forceinline__ int gload_i(const int* p) {
    return __hip_atomic_load(p, __ATOMIC_RELAXED, __HIP_MEMORY_SCOPE_AGENT);
}
__device__ __forceinline__ unsigned gload_u(const unsigned* p) {
    return __hip_atomic_load(p, __ATOMIC_RELAXED, __HIP_MEMORY_SCOPE_AGENT);
}
__device__ __forceinline__ void gstore_us(unsigned short* p, unsigned short v) {
    __hip_atomic_store(p, v, __ATOMIC_RELAXED, __HIP_MEMORY_SCOPE_AGENT);
}
__device__ __forceinline__ void gstore_stamp(int* p, int v) {
    __hip_atomic_store(p, v, __ATOMIC_RELAXED, __HIP_MEMORY_SCOPE_AGENT);
}

struct bf16pair { __bf16 hi, lo; };
__device__ __forceinline__ bf16pair split2(float f) {
    bf16pair r;
    r.hi = (__bf16)f;
    r.lo = (__bf16)(f - (float)r.hi);
    return r;
}
__device__ __forceinline__ unsigned pk2(float a, float b) {
    return (unsigned)__builtin_bit_cast(unsigned short, (__bf16)a) |
           ((unsigned)__builtin_bit_cast(unsigned short, (__bf16)b) << 16);
}
__device__ __forceinline__ void st_pair(__bf16* p, __bf16 a, __bf16 b) {
    unsigned v = (unsigned)__builtin_bit_cast(unsigned short, a) |
                 ((unsigned)__builtin_bit_cast(unsigned short, b) << 16);
    *(unsigned*)p = v;
}
__device__ __forceinline__ float elu1(float v) {
    return v > 0.f ? v : (expf(v) - 1.f);
}

// Per-wave publish: this wave's stores drained (vmcnt0 is wave-level, covers
// all 64 lanes' stores), lane0 bumps the LDS counter; the finishing wave
// stores the global stamp. NO block barrier.
__device__ __forceinline__ void wave_pub(int* lds_ctr, int finish_old, int* stamp, int val) {
    asm volatile("s_waitcnt vmcnt(0)" ::: "memory");
    if ((threadIdx.x & 63) == 0) {
        int old = __hip_atomic_fetch_add(lds_ctr, 1, __ATOMIC_RELAXED,
                                         __HIP_MEMORY_SCOPE_WORKGROUP);
        if (old == finish_old) gstore_stamp(stamp, val);
    }
}
// Every wave polls all 32 slice stamps independently (lane&31 -> stamp).
__device__ __forceinline__ void poll_wave(const int* st, int target) {
    const int* p = st + (threadIdx.x & 31);
    while (true) {
        int v = gload_i(p);
        if (__all(v >= target)) break;
        __builtin_amdgcn_s_sleep(1);
    }
}

__global__ void dlstm_init(float* __restrict__ ws) {
    int idx = threadIdx.x;
    if (idx < N_ST) ((int*)ws + OFF_ST)[idx] = 0;
}

__global__ __launch_bounds__(THREADS, 2) void dlstm_main(
    const float* __restrict__ x,
    const float* __restrict__ W1, const float* __restrict__ g1, const float* __restrict__ b1,
    const float* __restrict__ W2, const float* __restrict__ g2, const float* __restrict__ b2,
    const float* __restrict__ W3, const float* __restrict__ g3, const float* __restrict__ b3,
    float* __restrict__ out, float* __restrict__ ws)
{
    const int tid = threadIdx.x;
    const int bid = blockIdx.x;
    const int g = bid & 3;
    const int s = bid >> 2;          // 0..31 feature slice
    const int r0 = g * RPG;

    const int lane = tid & 63;
    const int wv   = tid >> 6;       // wave 0..7 (k-split)
    const int col  = lane & 15;
    const int kq   = lane >> 4;
    const int er   = tid >> 5;       // row 0..15 for elementwise phases
    const int l32  = tid & 31;

    float* a1 = ws + OFF_A1;
    float* a2 = ws + OFF_A2;
    unsigned short* cbu = (unsigned short*)(ws + OFF_CB);
    float* p3 = ws + OFF_P3;
    int* stb   = (int*)ws + OFF_ST;
    int* st_a1 = stb + 0   + g * 32;
    int* st_a2 = stb + 128 + g * 32;
    int* st_p3 = stb + 256 + g * 32;
    int* st_cb = stb + 384 + g * 32;

    __shared__ __bf16 zh[16][776];   // x: [0..255], c: [256..767]; h1/h2: [0..511]
    __shared__ float comb[8][3][256];
    __shared__ float slab[16][48];   // [i|16+i|32+i] = gates h,c,f
    __shared__ float stats[16][2];
    __shared__ int syncc[4];         // monotonic LDS pub counters: a1,a2,p3,cb

    if (tid < 4) syncc[tid] = 0;

    // ---------------- hoisted LN params (loop-invariant) ----------------
    float2 g1v[8], b1v[8], g2v[8], b2v[8];
    #pragma unroll
    for (int j = 0; j < 8; ++j) {
        int k = j * 64 + l32 * 2;
        g1v[j] = *(const float2*)(g1 + k); b1v[j] = *(const float2*)(b1 + k);
        g2v[j] = *(const float2*)(g2 + k); b2v[j] = *(const float2*)(b2 + k);
    }
    float g3h = 0.f, g3c = 0.f, g3f = 0.f, b3h = 0.f, b3c = 0.f, b3f = 0.f;
    if (tid < 256) {
        int i = tid & 15; int h = 16 * s + i;
        g3h = g3[h];        g3c = g3[HDIM + h];        g3f = g3[2 * HDIM + h];
        b3h = b3[h];        b3c = b3[HDIM + h];        b3f = b3[2 * HDIM + h];
    }

    // ---------------- weights -> register fragments (hi/lo split) ----------------
    bf16x8 w1h[3], w1l[3], w2h[2], w2l[2], w3h[3][2], w3l[3][2];
    #pragma unroll
    for (int ks = 0; ks < 3; ++ks) {
        int k0 = wv * 96 + ks * 32 + kq * 8;
        const float* p = W1 + (size_t)(16 * s + col) * K1 + k0;
        #pragma unroll
        for (int e = 0; e < 8; ++e) {
            bf16pair pr = split2(p[e]);
            w1h[ks][e] = pr.hi; w1l[ks][e] = pr.lo;
        }
    }
    #pragma unroll
    for (int ks = 0; ks < 2; ++ks) {
        int k0 = wv * 64 + ks * 32 + kq * 8;
        const float* p = W2 + (size_t)(16 * s + col) * HDIM + k0;
        #pragma unroll
        for (int e = 0; e < 8; ++e) {
            bf16pair pr = split2(p[e]);
            w2h[ks][e] = pr.hi; w2l[ks][e] = pr.lo;
        }
    }
    #pragma unroll
    for (int tb = 0; tb < 3; ++tb) {
        #pragma unroll
        for (int ks = 0; ks < 2; ++ks) {
            int k0 = wv * 64 + ks * 32 + kq * 8;
            const float* p = W3 + (size_t)(tb * HDIM + 16 * s + col) * HDIM + k0;
            #pragma unroll
            for (int e = 0; e < 8; ++e) {
                bf16pair pr = split2(p[e]);
                w3h[tb][ks][e] = pr.hi; w3l[tb][ks][e] = pr.lo;
            }
        }
    }

    // distributed cell state: thread tid<256 owns c[row = tid>>4][col = 16s + (tid&15)]
    float creg = 0.f;

    // ---------------- prologue: zero c-region; x(0) -> zh; GEMM1-x(0) ----------------
    #pragma unroll
    for (int k = 0; k < 8; ++k)
        st_pair(&zh[er][256 + 2 * l32 + 64 * k], (__bf16)0.f, (__bf16)0.f);
    float2 xr[4];
    {
        const float* xrow = x + (size_t)(r0 + er) * IDIM;
        #pragma unroll
        for (int j = 0; j < 4; ++j) xr[j] = *(const float2*)(xrow + j * 64 + l32 * 2);
        unsigned* zrow = (unsigned*)&zh[er][0];
        #pragma unroll
        for (int j = 0; j < 4; ++j) zrow[j * 32 + l32] = pk2(xr[j].x, xr[j].y);
    }
    __syncthreads();
    f32x4 acc = {0.f, 0.f, 0.f, 0.f};
    #pragma unroll
    for (int ks = 0; ks < 3; ++ks) {
        int kb = wv * 96 + ks * 32;
        if (kb < IDIM) {
            bf16x8 ah = *(const bf16x8*)&zh[col][kb + kq * 8];
            acc = MFMA(ah, w1h[ks], acc);
            acc = MFMA(ah, w1l[ks], acc);
        }
    }

    #pragma unroll 1
    for (int t = 0; t < T_STEPS; ++t) {
        unsigned* zrow = (unsigned*)&zh[er][0];
        // ========== stage 1: c exchange (poll deferred from t-1) + GEMM1-c ==========
        if (t > 0) {
            poll_wave(st_cb, t);
            const unsigned* cbrow = (const unsigned*)cbu + (size_t)(r0 + er) * (HDIM / 2);
            #pragma unroll
            for (int j = 0; j < 8; ++j)
                zrow[128 + j * 32 + l32] = gload_u(cbrow + j * 32 + l32);
        }
        __syncthreads();                                              // Bc0
        #pragma unroll
        for (int ks = 0; ks < 3; ++ks) {
            int kb = wv * 96 + ks * 32;
            if (kb >= IDIM) {
                bf16x8 ah = *(const bf16x8*)&zh[col][kb + kq * 8];
                acc = MFMA(ah, w1h[ks], acc);
                acc = MFMA(ah, w1l[ks], acc);
            }
        }
        #pragma unroll
        for (int i = 0; i < 4; ++i) comb[wv][0][(kq * 4 + i) * 16 + col] = acc[i];
        __syncthreads();                                              // Bc1
        if (tid < 128) {             // waves 0,1: reduce + store + self-publish
            int r = tid >> 3, fp = tid & 7;
            int i0 = r * 16 + fp * 2;
            float v0 = 0.f, v1 = 0.f;
            #pragma unroll
            for (int w = 0; w < 8; ++w) { v0 += comb[w][0][i0]; v1 += comb[w][0][i0 + 1]; }
            gstore2(&a1[(size_t)(r0 + r) * HDIM + 16 * s + fp * 2], v0, v1);
            wave_pub(&syncc[0], 2 * t + 1, &st_a1[s], t + 1);
        }

        // ================= stage 2: h1 = elu(LN(a1)); GEMM2 =================
        poll_wave(st_a1, t + 1);
        {
            size_t arow = (size_t)(r0 + er) * HDIM;
            float2 va[8]; float s1 = 0.f, s2 = 0.f;
            #pragma unroll
            for (int j = 0; j < 8; ++j) {
                va[j] = gload2(a1 + arow + j * 64 + l32 * 2);
                s1 += va[j].x + va[j].y; s2 += va[j].x * va[j].x + va[j].y * va[j].y;
            }
            s1 += __shfl_xor(s1, 1, 64); s2 += __shfl_xor(s2, 1, 64);
            s1 += __shfl_xor(s1, 2, 64); s2 += __shfl_xor(s2, 2, 64);
            s1 += __shfl_xor(s1, 4, 64); s2 += __shfl_xor(s2, 4, 64);
            s1 += __shfl_xor(s1, 8, 64); s2 += __shfl_xor(s2, 8, 64);
            s1 += __shfl_xor(s1, 16, 64); s2 += __shfl_xor(s2, 16, 64);
            float mu = s1 * (1.f / HDIM);
            float var = s2 * (1.f / HDIM) - mu * mu;
            float rs = rsqrtf(var + 1e-5f);
            #pragma unroll
            for (int j = 0; j < 8; ++j) {
                int k = j * 64 + l32 * 2;
                float v0 = elu1((va[j].x - mu) * rs * g1v[j].x + b1v[j].x);
                float v1 = elu1((va[j].y - mu) * rs * g1v[j].y + b1v[j].y);
                st_pair(&zh[er][k], (__bf16)v0, (__bf16)v1);
            }
        }
        __syncthreads();                                              // B5
        {
            f32x4 acc2 = {0.f, 0.f, 0.f, 0.f};
            #pragma unroll
            for (int ks = 0; ks < 2; ++ks) {
                int k0 = wv * 64 + ks * 32 + kq * 8;
                bf16x8 ah = *(const bf16x8*)&zh[col][k0];
                acc2 = MFMA(ah, w2h[ks], acc2);
                acc2 = MFMA(ah, w2l[ks], acc2);
            }
            #pragma unroll
            for (int i = 0; i < 4; ++i) comb[wv][0][(kq * 4 + i) * 16 + col] = acc2[i];
        }
        __syncthreads();                                              // B6
        if (tid < 128) {
            int r = tid >> 3, fp = tid & 7;
            int i0 = r * 16 + fp * 2;
            float v0 = 0.f, v1 = 0.f;
            #pragma unroll
            for (int w = 0; w < 8; ++w) { v0 += comb[w][0][i0]; v1 += comb[w][0][i0 + 1]; }
            gstore2(&a2[(size_t)(r0 + r) * HDIM + 16 * s + fp * 2], v0, v1);
            wave_pub(&syncc[1], 2 * t + 1, &st_a2[s], t + 1);
        }

        // ================= stage 3: h2 = elu(LN(a2)); prefetch x(t+1); GEMM3 =================
        poll_wave(st_a2, t + 1);
        {
            {   // prefetch next x while a2 loads are in flight
                int tn = (t + 1 < T_STEPS) ? t + 1 : t;
                const float* xrow = x + ((size_t)tn * BATCH + r0 + er) * IDIM;
                #pragma unroll
                for (int j = 0; j < 4; ++j) xr[j] = *(const float2*)(xrow + j * 64 + l32 * 2);
            }
            size_t arow = (size_t)(r0 + er) * HDIM;
            float2 va[8]; float s1 = 0.f, s2 = 0.f;
            #pragma unroll
            for (int j = 0; j < 8; ++j) va[j] = gload2(a2 + arow + j * 64 + l32 * 2);
            #pragma unroll
            for (int j = 0; j < 8; ++j) {
                s1 += va[j].x + va[j].y; s2 += va[j].x * va[j].x + va[j].y * va[j].y;
            }
            s1 += __shfl_xor(s1, 1, 64); s2 += __shfl_xor(s2, 1, 64);
            s1 += __shfl_xor(s1, 2, 64); s2 += __shfl_xor(s2, 2, 64);
            s1 += __shfl_xor(s1, 4, 64); s2 += __shfl_xor(s2, 4, 64);
            s1 += __shfl_xor(s1, 8, 64); s2 += __shfl_xor(s2, 8, 64);
            s1 += __shfl_xor(s1, 16, 64); s2 += __shfl_xor(s2, 16, 64);
            float mu = s1 * (1.f / HDIM);
            float var = s2 * (1.f / HDIM) - mu * mu;
            float rs = rsqrtf(var + 1e-5f);
            #pragma unroll
            for (int j = 0; j < 8; ++j) {
                int k = j * 64 + l32 * 2;
                float v0 = elu1((va[j].x - mu) * rs * g2v[j].x + b2v[j].x);
                float v1 = elu1((va[j].y - mu) * rs * g2v[j].y + b2v[j].y);
                st_pair(&zh[er][k], (__bf16)v0, (__bf16)v1);
            }
        }
        __syncthreads();                                              // B8
        {
            f32x4 acc0 = {0.f,0.f,0.f,0.f}, acc1 = {0.f,0.f,0.f,0.f}, acc2 = {0.f,0.f,0.f,0.f};
            #pragma unroll
            for (int ks = 0; ks < 2; ++ks) {
                int k0 = wv * 64 + ks * 32 + kq * 8;
                bf16x8 ah = *(const bf16x8*)&zh[col][k0];
                acc0 = MFMA(ah, w3h[0][ks], acc0);
                acc0 = MFMA(ah, w3l[0][ks], acc0);
                acc1 = MFMA(ah, w3h[1][ks], acc1);
                acc1 = MFMA(ah, w3l[1][ks], acc1);
                acc2 = MFMA(ah, w3h[2][ks], acc2);
                acc2 = MFMA(ah, w3l[2][ks], acc2);
            }
            #pragma unroll
            for (int i = 0; i < 4; ++i) {
                comb[wv][0][(kq * 4 + i) * 16 + col] = acc0[i];
                comb[wv][1][(kq * 4 + i) * 16 + col] = acc1[i];
                comb[wv][2][(kq * 4 + i) * 16 + col] = acc2[i];
            }
        }
        __syncthreads();                                              // B9
        if (tid < 384) {             // reduce into LDS slab only
            int o = tid * 2;
            int tb = o >> 8, idx = o & 255;
            int r = idx >> 4, f0 = idx & 15;
            float v0 = 0.f, v1 = 0.f;
            #pragma unroll
            for (int w = 0; w < 8; ++w) { v0 += comb[w][tb][idx]; v1 += comb[w][tb][idx + 1]; }
            slab[r][tb * 16 + f0] = v0;
            slab[r][tb * 16 + f0 + 1] = v1;
        }
        {   // x(t+1) -> zh x-region (GEMM3 done with zh at B9)
            #pragma unroll
            for (int j = 0; j < 4; ++j) zrow[j * 32 + l32] = pk2(xr[j].x, xr[j].y);
        }
        __syncthreads();                                              // B10
        {
            float va_ = slab[er][l32];
            float vb_ = (l32 < 16) ? slab[er][32 + l32] : 0.f;
            float s1 = va_ + vb_;
            float s2 = va_ * va_ + vb_ * vb_;
            s1 += __shfl_xor(s1, 1, 64); s2 += __shfl_xor(s2, 1, 64);
            s1 += __shfl_xor(s1, 2, 64); s2 += __shfl_xor(s2, 2, 64);
            s1 += __shfl_xor(s1, 4, 64); s2 += __shfl_xor(s2, 4, 64);
            s1 += __shfl_xor(s1, 8, 64); s2 += __shfl_xor(s2, 8, 64);
            s1 += __shfl_xor(s1, 16, 64); s2 += __shfl_xor(s2, 16, 64);
            if (l32 == 0) gstore2(&p3[((size_t)(r0 + er) * NSLICE + s) * 2], s1, s2);
        }
        wave_pub(&syncc[2], 8 * t + 7, &st_p3[s], t + 1);   // all 8 waves

        // -------- hoisted GEMM1-x for t+1: fills the p3 round-trip window --------
        acc[0] = 0.f; acc[1] = 0.f; acc[2] = 0.f; acc[3] = 0.f;
        #pragma unroll
        for (int ks = 0; ks < 3; ++ks) {
            int kb = wv * 96 + ks * 32;
            if (kb < IDIM) {
                bf16x8 ah = *(const bf16x8*)&zh[col][kb + kq * 8];
                acc = MFMA(ah, w1h[ks], acc);
                acc = MFMA(ah, w1l[ks], acc);
            }
        }

        // ================= epilogue: LN3 stats, own-slice gates, c update =================
        poll_wave(st_p3, t + 1);
        {
            float2 pv = gload2(&p3[((size_t)(r0 + er) * NSLICE + l32) * 2]);
            float s1 = pv.x, s2 = pv.y;
            s1 += __shfl_xor(s1, 1, 64); s2 += __shfl_xor(s2, 1, 64);
            s1 += __shfl_xor(s1, 2, 64); s2 += __shfl_xor(s2, 2, 64);
            s1 += __shfl_xor(s1, 4, 64); s2 += __shfl_xor(s2, 4, 64);
            s1 += __shfl_xor(s1, 8, 64); s2 += __shfl_xor(s2, 8, 64);
            s1 += __shfl_xor(s1, 16, 64); s2 += __shfl_xor(s2, 16, 64);
            float mu = s1 * (1.f / H3);
            float var = s2 * (1.f / H3) - mu * mu;
            float rs = rsqrtf(var + 1e-5f);
            if (l32 == 0) { stats[er][0] = mu; stats[er][1] = rs; }
        }
        __syncthreads();                                              // B12
        if (tid < 256) {             // waves 0..3: c first, cb store+stamp, then h out
            int r = tid >> 4, i = tid & 15;
            int h = 16 * s + i;
            float mu = stats[r][0], rs = stats[r][1];
            float ocn = (slab[r][16 + i] - mu) * rs * g3c + b3c;
            float ofn = (slab[r][32 + i] - mu) * rs * g3f + b3f;
            float sig = 1.f / (1.f + expf(-ofn));
            float fv = sig * sig;
            float cnew = fv * elu1(ocn) + (1.f - fv) * creg;
            creg = cnew;
            gstore_us(&cbu[(size_t)(r0 + r) * HDIM + h],
                      __builtin_bit_cast(unsigned short, (__bf16)cnew));
            wave_pub(&syncc[3], 4 * t + 3, &st_cb[s], t + 1);
            // HBM out stores AFTER the stamp: drain happens off critical path
            float ohn = (slab[r][i] - mu) * rs * g3h + b3h;
            out[((size_t)t * BATCH + r0 + r) * HDIM + h] = elu1(ohn);
            if (t == T_STEPS - 1)
                out[(size_t)T_STEPS * BATCH * HDIM + (size_t)(r0 + r) * HDIM + h] = cnew;
        }
        // cb poll deferred to stage 1 of t+1 (window filled by h-out + poll skew)
    }
}

extern "C" void kernel_launch(void* const* d_in, const int* in_sizes, int n_in,
                              void* d_out, int out_size, void* d_ws, size_t ws_size,
                              hipStream_t stream) {
    const float* x  = (const float*)d_in[0];
    const float* W1 = (const float*)d_in[1];
    const float* g1 = (const float*)d_in[2];
    const float* b1 = (const float*)d_in[3];
    const float* W2 = (const float*)d_in[4];
    const float* g2 = (const float*)d_in[5];
    const float* b2 = (const float*)d_in[6];
    const float* W3 = (const float*)d_in[7];
    const float* g3 = (const float*)d_in[8];
    const float* b3 = (const float*)d_in[9];
    float* out = (float*)d_out;
    float* ws  = (float*)d_ws;

    dlstm_init<<<1, 512, 0, stream>>>(ws);
    dlstm_main<<<NGROUP * NSLICE, THREADS, 0, stream>>>(x, W1, g1, b1, W2, g2, b2, W3, g3, b3, out, ws);
}

// Round 6
// 25782.452 us; speedup vs baseline: 1.4871x; 1.4871x over previous
//
#include <hip/hip_runtime.h>
#include <math.h>

#define T_STEPS 2048
#define BATCH   64
#define IDIM    256
#define HDIM    512
#define K1      768
#define H3      1536
#define NGROUP  4
#define NSLICE  32
#define RPG     16
#define THREADS 512

// ---------------------------------------------------------------------------
// Round-6 = round-0 (proven 25.98 ms) + two minimal diffs:
//  (A) single-poller: only wave 0 polls the 32 slice stamps, then a
//      __syncthreads releases the block. 8x less LLC read pressure on the
//      stamp lines -> producer stamp stores land faster (R5 showed
//      aggressive polling self-delays the stamps it waits on).
//  (B) h/out HBM stores moved AFTER the cb publish: round-0's publish
//      barrier drained the ~900cy HBM out-store before tid0 could stamp cb,
//      putting that drain on the serial cross-block chain every step. Now
//      the cb stamp leaves first; the out-store drain folds into next
//      step's b1 (off the stamp path).
// Dataflow, MFMA order, reduces: byte-identical to round-0.
// ---------------------------------------------------------------------------

// Workspace layout (floats)
#define OFF_A1  0          // 64*512 f32
#define OFF_A2  32768      // 64*512 f32
#define OFF_CB  65536      // 64*512 bf16 (packed, stored as ushort)
#define OFF_P3  98304      // 64 rows * 32 slices * 2 f32
#define OFF_ST  102400     // stamps: 4 stages * 4 groups * 32 ints

typedef __attribute__((ext_vector_type(8))) __bf16 bf16x8;
typedef __attribute__((ext_vector_type(4))) float f32x4;

__device__ __forceinline__ f32x4 MFMA(bf16x8 a, bf16x8 b, f32x4 c) {
    return __builtin_amdgcn_mfma_f32_16x16x32_bf16(a, b, c, 0, 0, 0);
}

__device__ __forceinline__ float gload(const float* p) {
    return __hip_atomic_load(p, __ATOMIC_RELAXED, __HIP_MEMORY_SCOPE_AGENT);
}
__device__ __forceinline__ void gstore(float* p, float v) {
    __hip_atomic_store(p, v, __ATOMIC_RELAXED, __HIP_MEMORY_SCOPE_AGENT);
}
__device__ __forceinline__ float2 gload2(const float* p) {
    unsigned long long v = __hip_atomic_load((const unsigned long long*)p,
                                             __ATOMIC_RELAXED, __HIP_MEMORY_SCOPE_AGENT);
    return __builtin_bit_cast(float2, v);
}
__device__ __forceinline__ void gstore2(float* p, float a, float b) {
    float2 v = {a, b};
    __hip_atomic_store((unsigned long long*)p, __builtin_bit_cast(unsigned long long, v),
                       __ATOMIC_RELAXED, __HIP_MEMORY_SCOPE_AGENT);
}
__device__ __forceinline__ int gload_i(const int* p) {
    return __hip_atomic_load(p, __ATOMIC_RELAXED, __HIP_MEMORY_SCOPE_AGENT);
}
__device__ __forceinline__ unsigned gload_u(const unsigned* p) {
    return __hip_atomic_load(p, __ATOMIC_RELAXED, __HIP_MEMORY_SCOPE_AGENT);
}
__device__ __forceinline__ void gstore_us(unsigned short* p, unsigned short v) {
    __hip_atomic_store(p, v, __ATOMIC_RELAXED, __HIP_MEMORY_SCOPE_AGENT);
}

struct bf16pair { __bf16 hi, lo; };
__device__ __forceinline__ bf16pair split2(float f) {
    bf16pair r;
    r.hi = (__bf16)f;
    r.lo = (__bf16)(f - (float)r.hi);
    return r;
}
__device__ __forceinline__ unsigned pk2(float a, float b) {
    return (unsigned)__builtin_bit_cast(unsigned short, (__bf16)a) |
           ((unsigned)__builtin_bit_cast(unsigned short, (__bf16)b) << 16);
}
__device__ __forceinline__ void st_pair(__bf16* p, __bf16 a, __bf16 b) {
    unsigned v = (unsigned)__builtin_bit_cast(unsigned short, a) |
                 ((unsigned)__builtin_bit_cast(unsigned short, b) << 16);
    *(unsigned*)p = v;
}
__device__ __forceinline__ float elu1(float v) {
    return v > 0.f ? v : (expf(v) - 1.f);
}

// Producer publish: data stores -> __syncthreads (drains every thread's vmcnt;
// agent-scope stores are LLC-visible) -> one stamp store.
__device__ __forceinline__ void publish(int* stamp_s, int val) {
    __syncthreads();
    if (threadIdx.x == 0)
        __hip_atomic_store(stamp_s, val, __ATOMIC_RELAXED, __HIP_MEMORY_SCOPE_AGENT);
}
// Single-poller: wave 0 polls all 32 slice stamps (lane&31 -> stamp); the
// release barrier frees the other 7 waves. 8x less LLC poll traffic than
// all-wave polling (R5 post-mortem: aggressive polling delays the stamps).
__device__ __forceinline__ void poll_release(const int* st, int target) {
    if (threadIdx.x < 64) {
        const int* p = st + (threadIdx.x & 31);
        while (true) {
            int v = gload_i(p);
            if (__all(v >= target)) break;
            __builtin_amdgcn_s_sleep(1);
        }
    }
    __syncthreads();
}

__global__ void dlstm_init(float* __restrict__ ws) {
    int idx = threadIdx.x;
    if (idx < 512) ((int*)(ws + OFF_ST))[idx] = 0;
}

__global__ __launch_bounds__(THREADS, 2) void dlstm_main(
    const float* __restrict__ x,
    const float* __restrict__ W1, const float* __restrict__ g1, const float* __restrict__ b1,
    const float* __restrict__ W2, const float* __restrict__ g2, const float* __restrict__ b2,
    const float* __restrict__ W3, const float* __restrict__ g3, const float* __restrict__ b3,
    float* __restrict__ out, float* __restrict__ ws)
{
    const int tid = threadIdx.x;
    const int bid = blockIdx.x;
    const int g = bid & 3;
    const int s = bid >> 2;          // 0..31 feature slice
    const int r0 = g * RPG;

    const int lane = tid & 63;
    const int wv   = tid >> 6;       // wave 0..7 (k-split)
    const int col  = lane & 15;
    const int kq   = lane >> 4;
    const int er   = tid >> 5;       // row 0..15 for elementwise phases
    const int l32  = tid & 31;

    float* a1 = ws + OFF_A1;
    float* a2 = ws + OFF_A2;
    unsigned short* cbu = (unsigned short*)(ws + OFF_CB);
    float* p3 = ws + OFF_P3;
    int* stb   = (int*)(ws + OFF_ST);
    int* st_a1 = stb + 0   + g * 32;
    int* st_a2 = stb + 128 + g * 32;
    int* st_p3 = stb + 256 + g * 32;
    int* st_cb = stb + 384 + g * 32;

    __shared__ __bf16 zh[16][776];   // 388 dwords/row, 388%32==4
    __shared__ float comb[8][3][256];
    __shared__ float slab[16][48];   // [i|16+i|32+i] = gates h,c,f
    __shared__ float stats[16][2];

    // ---------------- hoisted LN params (loop-invariant) ----------------
    float2 g1v[8], b1v[8], g2v[8], b2v[8];
    #pragma unroll
    for (int j = 0; j < 8; ++j) {
        int k = j * 64 + l32 * 2;
        g1v[j] = *(const float2*)(g1 + k); b1v[j] = *(const float2*)(b1 + k);
        g2v[j] = *(const float2*)(g2 + k); b2v[j] = *(const float2*)(b2 + k);
    }
    float g3h = 0.f, g3c = 0.f, g3f = 0.f, b3h = 0.f, b3c = 0.f, b3f = 0.f;
    if (tid < 256) {
        int i = tid & 15; int h = 16 * s + i;
        g3h = g3[h];        g3c = g3[HDIM + h];        g3f = g3[2 * HDIM + h];
        b3h = b3[h];        b3c = b3[HDIM + h];        b3f = b3[2 * HDIM + h];
    }

    // ---------------- weights -> register fragments (hi/lo split) ----------------
    bf16x8 w1h[3], w1l[3], w2h[2], w2l[2], w3h[3][2], w3l[3][2];
    #pragma unroll
    for (int ks = 0; ks < 3; ++ks) {
        int k0 = wv * 96 + ks * 32 + kq * 8;
        const float* p = W1 + (size_t)(16 * s + col) * K1 + k0;
        #pragma unroll
        for (int e = 0; e < 8; ++e) {
            bf16pair pr = split2(p[e]);
            w1h[ks][e] = pr.hi; w1l[ks][e] = pr.lo;
        }
    }
    #pragma unroll
    for (int ks = 0; ks < 2; ++ks) {
        int k0 = wv * 64 + ks * 32 + kq * 8;
        const float* p = W2 + (size_t)(16 * s + col) * HDIM + k0;
        #pragma unroll
        for (int e = 0; e < 8; ++e) {
            bf16pair pr = split2(p[e]);
            w2h[ks][e] = pr.hi; w2l[ks][e] = pr.lo;
        }
    }
    #pragma unroll
    for (int tb = 0; tb < 3; ++tb) {       // aligned ownership: rows tb*512 + 16s + col
        #pragma unroll
        for (int ks = 0; ks < 2; ++ks) {
            int k0 = wv * 64 + ks * 32 + kq * 8;
            const float* p = W3 + (size_t)(tb * HDIM + 16 * s + col) * HDIM + k0;
            #pragma unroll
            for (int e = 0; e < 8; ++e) {
                bf16pair pr = split2(p[e]);
                w3h[tb][ks][e] = pr.hi; w3l[tb][ks][e] = pr.lo;
            }
        }
    }

    // distributed cell state: thread tid<256 owns c[row = tid>>4][col = 16s + (tid&15)]
    float creg = 0.f;

    // prefetch + pre-pack x for t=0
    float2 xr[4];
    unsigned xb[4];
    {
        const float* xrow = x + (size_t)(r0 + er) * IDIM;
        #pragma unroll
        for (int j = 0; j < 4; ++j) xr[j] = *(const float2*)(xrow + j * 64 + l32 * 2);
        #pragma unroll
        for (int j = 0; j < 4; ++j) xb[j] = pk2(xr[j].x, xr[j].y);
    }

    #pragma unroll 1
    for (int t = 0; t < T_STEPS; ++t) {
        unsigned* zrow = (unsigned*)&zh[er][0];
        // ================= stage 1: x-plane + GEMM1(x part) =================
        #pragma unroll
        for (int j = 0; j < 4; ++j) zrow[j * 32 + l32] = xb[j];
        __syncthreads();
        f32x4 acc = {0.f, 0.f, 0.f, 0.f};
        #pragma unroll
        for (int ks = 0; ks < 3; ++ks) {
            int kb = wv * 96 + ks * 32;
            if (kb < IDIM) {
                bf16x8 ah = *(const bf16x8*)&zh[col][kb + kq * 8];
                acc = MFMA(ah, w1h[ks], acc);
                acc = MFMA(ah, w1l[ks], acc);
            }
        }
        // ---- c exchange: poll prev-step cb stamps (wave0), raw uint copy LLC->LDS ----
        if (t > 0) {
            poll_release(st_cb, t);
            const unsigned* cbrow = (const unsigned*)cbu + (size_t)(r0 + er) * (HDIM / 2);
            #pragma unroll
            for (int j = 0; j < 8; ++j)
                zrow[128 + j * 32 + l32] = gload_u(cbrow + j * 32 + l32);
        } else {
            #pragma unroll
            for (int j = 0; j < 8; ++j) zrow[128 + j * 32 + l32] = 0u;
        }
        __syncthreads();
        #pragma unroll
        for (int ks = 0; ks < 3; ++ks) {
            int kb = wv * 96 + ks * 32;
            if (kb >= IDIM) {
                bf16x8 ah = *(const bf16x8*)&zh[col][kb + kq * 8];
                acc = MFMA(ah, w1h[ks], acc);
                acc = MFMA(ah, w1l[ks], acc);
            }
        }
        #pragma unroll
        for (int i = 0; i < 4; ++i) comb[wv][0][(kq * 4 + i) * 16 + col] = acc[i];
        __syncthreads();
        if (tid < 128) {
            int r = tid >> 3, fp = tid & 7;
            int i0 = r * 16 + fp * 2;
            float v0 = 0.f, v1 = 0.f;
            #pragma unroll
            for (int w = 0; w < 8; ++w) { v0 += comb[w][0][i0]; v1 += comb[w][0][i0 + 1]; }
            gstore2(&a1[(size_t)(r0 + r) * HDIM + 16 * s + fp * 2], v0, v1);
        }
        publish(&st_a1[s], t + 1);

        // ================= stage 2: h1 = elu(LN(a1)); GEMM2 =================
        poll_release(st_a1, t + 1);
        {
            size_t arow = (size_t)(r0 + er) * HDIM;
            float2 va[8]; float s1 = 0.f, s2 = 0.f;
            #pragma unroll
            for (int j = 0; j < 8; ++j) {
                va[j] = gload2(a1 + arow + j * 64 + l32 * 2);
                s1 += va[j].x + va[j].y; s2 += va[j].x * va[j].x + va[j].y * va[j].y;
            }
            s1 += __shfl_xor(s1, 1, 64); s2 += __shfl_xor(s2, 1, 64);
            s1 += __shfl_xor(s1, 2, 64); s2 += __shfl_xor(s2, 2, 64);
            s1 += __shfl_xor(s1, 4, 64); s2 += __shfl_xor(s2, 4, 64);
            s1 += __shfl_xor(s1, 8, 64); s2 += __shfl_xor(s2, 8, 64);
            s1 += __shfl_xor(s1, 16, 64); s2 += __shfl_xor(s2, 16, 64);
            float mu = s1 * (1.f / HDIM);
            float var = s2 * (1.f / HDIM) - mu * mu;
            float rs = rsqrtf(var + 1e-5f);
            #pragma unroll
            for (int j = 0; j < 8; ++j) {
                int k = j * 64 + l32 * 2;
                float v0 = elu1((va[j].x - mu) * rs * g1v[j].x + b1v[j].x);
                float v1 = elu1((va[j].y - mu) * rs * g1v[j].y + b1v[j].y);
                st_pair(&zh[er][k], (__bf16)v0, (__bf16)v1);
            }
        }
        __syncthreads();
        {
            f32x4 acc2 = {0.f, 0.f, 0.f, 0.f};
            #pragma unroll
            for (int ks = 0; ks < 2; ++ks) {
                int k0 = wv * 64 + ks * 32 + kq * 8;
                bf16x8 ah = *(const bf16x8*)&zh[col][k0];
                acc2 = MFMA(ah, w2h[ks], acc2);
                acc2 = MFMA(ah, w2l[ks], acc2);
            }
            #pragma unroll
            for (int i = 0; i < 4; ++i) comb[wv][0][(kq * 4 + i) * 16 + col] = acc2[i];
        }
        __syncthreads();
        if (tid < 128) {
            int r = tid >> 3, fp = tid & 7;
            int i0 = r * 16 + fp * 2;
            float v0 = 0.f, v1 = 0.f;
            #pragma unroll
            for (int w = 0; w < 8; ++w) { v0 += comb[w][0][i0]; v1 += comb[w][0][i0 + 1]; }
            gstore2(&a2[(size_t)(r0 + r) * HDIM + 16 * s + fp * 2], v0, v1);
        }
        publish(&st_a2[s], t + 1);

        // ================= stage 3: h2 = elu(LN(a2)); prefetch x(t+1); GEMM3 =================
        poll_release(st_a2, t + 1);
        {
            size_t arow = (size_t)(r0 + er) * HDIM;
            float2 va[8]; float s1 = 0.f, s2 = 0.f;
            #pragma unroll
            for (int j = 0; j < 8; ++j) va[j] = gload2(a2 + arow + j * 64 + l32 * 2);
            {   // prefetch next x while LN loads are in flight
                int tn = (t + 1 < T_STEPS) ? t + 1 : t;
                const float* xrow = x + ((size_t)tn * BATCH + r0 + er) * IDIM;
                #pragma unroll
                for (int j = 0; j < 4; ++j) xr[j] = *(const float2*)(xrow + j * 64 + l32 * 2);
            }
            #pragma unroll
            for (int j = 0; j < 8; ++j) {
                s1 += va[j].x + va[j].y; s2 += va[j].x * va[j].x + va[j].y * va[j].y;
            }
            s1 += __shfl_xor(s1, 1, 64); s2 += __shfl_xor(s2, 1, 64);
            s1 += __shfl_xor(s1, 2, 64); s2 += __shfl_xor(s2, 2, 64);
            s1 += __shfl_xor(s1, 4, 64); s2 += __shfl_xor(s2, 4, 64);
            s1 += __shfl_xor(s1, 8, 64); s2 += __shfl_xor(s2, 8, 64);
            s1 += __shfl_xor(s1, 16, 64); s2 += __shfl_xor(s2, 16, 64);
            float mu = s1 * (1.f / HDIM);
            float var = s2 * (1.f / HDIM) - mu * mu;
            float rs = rsqrtf(var + 1e-5f);
            #pragma unroll
            for (int j = 0; j < 8; ++j) {
                int k = j * 64 + l32 * 2;
                float v0 = elu1((va[j].x - mu) * rs * g2v[j].x + b2v[j].x);
                float v1 = elu1((va[j].y - mu) * rs * g2v[j].y + b2v[j].y);
                st_pair(&zh[er][k], (__bf16)v0, (__bf16)v1);
            }
        }
        __syncthreads();
        {
            f32x4 acc0 = {0.f,0.f,0.f,0.f}, acc1 = {0.f,0.f,0.f,0.f}, acc2 = {0.f,0.f,0.f,0.f};
            #pragma unroll
            for (int ks = 0; ks < 2; ++ks) {
                int k0 = wv * 64 + ks * 32 + kq * 8;
                bf16x8 ah = *(const bf16x8*)&zh[col][k0];
                acc0 = MFMA(ah, w3h[0][ks], acc0);
                acc0 = MFMA(ah, w3l[0][ks], acc0);
                acc1 = MFMA(ah, w3h[1][ks], acc1);
                acc1 = MFMA(ah, w3l[1][ks], acc1);
                acc2 = MFMA(ah, w3h[2][ks], acc2);
                acc2 = MFMA(ah, w3l[2][ks], acc2);
            }
            #pragma unroll
            for (int i = 0; i < 4; ++i) {
                comb[wv][0][(kq * 4 + i) * 16 + col] = acc0[i];
                comb[wv][1][(kq * 4 + i) * 16 + col] = acc1[i];
                comb[wv][2][(kq * 4 + i) * 16 + col] = acc2[i];
            }
        }
        __syncthreads();
        if (tid < 384) {             // reduce into LDS slab only
            int o = tid * 2;
            int tb = o >> 8, idx = o & 255;
            int r = idx >> 4, f0 = idx & 15;
            float v0 = 0.f, v1 = 0.f;
            #pragma unroll
            for (int w = 0; w < 8; ++w) { v0 += comb[w][tb][idx]; v1 += comb[w][tb][idx + 1]; }
            slab[r][tb * 16 + f0] = v0;
            slab[r][tb * 16 + f0 + 1] = v1;
        }
        __syncthreads();
        {
            float va_ = slab[er][l32];
            float vb_ = (l32 < 16) ? slab[er][32 + l32] : 0.f;
            float s1 = va_ + vb_;
            float s2 = va_ * va_ + vb_ * vb_;
            s1 += __shfl_xor(s1, 1, 64); s2 += __shfl_xor(s2, 1, 64);
            s1 += __shfl_xor(s1, 2, 64); s2 += __shfl_xor(s2, 2, 64);
            s1 += __shfl_xor(s1, 4, 64); s2 += __shfl_xor(s2, 4, 64);
            s1 += __shfl_xor(s1, 8, 64); s2 += __shfl_xor(s2, 8, 64);
            s1 += __shfl_xor(s1, 16, 64); s2 += __shfl_xor(s2, 16, 64);
            if (l32 == 0) gstore2(&p3[((size_t)(r0 + er) * NSLICE + s) * 2], s1, s2);
        }
        publish(&st_p3[s], t + 1);

        // ================= epilogue (distributed): LN3 stats, own-slice gates, c update =================
        poll_release(st_p3, t + 1);
        {
            float2 pv = gload2(&p3[((size_t)(r0 + er) * NSLICE + l32) * 2]);
            float s1 = pv.x, s2 = pv.y;
            s1 += __shfl_xor(s1, 1, 64); s2 += __shfl_xor(s2, 1, 64);
            s1 += __shfl_xor(s1, 2, 64); s2 += __shfl_xor(s2, 2, 64);
            s1 += __shfl_xor(s1, 4, 64); s2 += __shfl_xor(s2, 4, 64);
            s1 += __shfl_xor(s1, 8, 64); s2 += __shfl_xor(s2, 8, 64);
            s1 += __shfl_xor(s1, 16, 64); s2 += __shfl_xor(s2, 16, 64);
            float mu = s1 * (1.f / H3);
            float var = s2 * (1.f / H3) - mu * mu;
            float rs = rsqrtf(var + 1e-5f);
            if (l32 == 0) { stats[er][0] = mu; stats[er][1] = rs; }
        }
        __syncthreads();
        // gates + c update + cb store BEFORE publish; HBM out stores AFTER
        int r_ = 0, i_ = 0;
        float mu_ = 0.f, rs_ = 0.f, cnew_ = 0.f;
        if (tid < 256) {
            r_ = tid >> 4; i_ = tid & 15;
            int h = 16 * s + i_;
            mu_ = stats[r_][0]; rs_ = stats[r_][1];
            float ocn = (slab[r_][16 + i_] - mu_) * rs_ * g3c + b3c;
            float ofn = (slab[r_][32 + i_] - mu_) * rs_ * g3f + b3f;
            float sig = 1.f / (1.f + expf(-ofn));
            float fv = sig * sig;
            cnew_ = fv * elu1(ocn) + (1.f - fv) * creg;
            creg = cnew_;
            gstore_us(&cbu[(size_t)(r_ + r0) * HDIM + h],
                      __builtin_bit_cast(unsigned short, (__bf16)cnew_));
        }
        publish(&st_cb[s], t + 1);   // barrier drains cb stores only; stamp leaves early
        if (tid < 256) {             // HBM out stores off the stamp path (drain at next b1)
            int h = 16 * s + i_;
            float ohn = (slab[r_][i_] - mu_) * rs_ * g3h + b3h;
            out[((size_t)t * BATCH + r0 + r_) * HDIM + h] = elu1(ohn);
            if (t == T_STEPS - 1)
                out[(size_t)T_STEPS * BATCH * HDIM + (size_t)(r0 + r_) * HDIM + h] = cnew_;
        }
        // pack next-step x (loads issued in stage 3 are long since complete)
        #pragma unroll
        for (int j = 0; j < 4; ++j) xb[j] = pk2(xr[j].x, xr[j].y);
        // cb poll deferred to stage 1 of t+1
    }
}

extern "C" void kernel_launch(void* const* d_in, const int* in_sizes, int n_in,
                              void* d_out, int out_size, void* d_ws, size_t ws_size,
                              hipStream_t stream) {
    const float* x  = (const float*)d_in[0];
    const float* W1 = (const float*)d_in[1];
    const float* g1 = (const float*)d_in[2];
    const float* b1 = (const float*)d_in[3];
    const float* W2 = (const float*)d_in[4];
    const float* g2 = (const float*)d_in[5];
    const float* b2 = (const float*)d_in[6];
    const float* W3 = (const float*)d_in[7];
    const float* g3 = (const float*)d_in[8];
    const float* b3 = (const float*)d_in[9];
    float* out = (float*)d_out;
    float* ws  = (float*)d_ws;

    dlstm_init<<<1, 512, 0, stream>>>(ws);
    dlstm_main<<<NGROUP * NSLICE, THREADS, 0, stream>>>(x, W1, g1, b1, W2, g2, b2, W3, g3, b3, out, ws);
}